// Round 1
// baseline (920.261 us; speedup 1.0000x reference)
//
#include <hip/hip_runtime.h>
#include <stdint.h>

#define N_TOK 343
#define NPAD  352          // 22*16
#define EMB   192
#define HD    32
#define SCALE 0.17677669529663689f
#define L2E   1.44269504088896341f

typedef __attribute__((ext_vector_type(8))) short short8;   // 8 bf16 (4 VGPRs)
typedef __attribute__((ext_vector_type(4))) short short4v;  // 4 bf16 (2 VGPRs)
typedef __attribute__((ext_vector_type(2))) unsigned uint2v;
typedef __attribute__((ext_vector_type(4))) float floatx4;  // MFMA C/D

__device__ __forceinline__ short f2bf(float f) {
  union { float f; unsigned u; } v; v.f = f;
  unsigned r = v.u + 0x7fffu + ((v.u >> 16) & 1u);  // RNE, finite inputs
  return (short)(r >> 16);
}
__device__ __forceinline__ float bf2f(short s) {
  union { unsigned u; float f; } v;
  v.u = ((unsigned)(unsigned short)s) << 16;
  return v.f;
}
__device__ __forceinline__ unsigned cvtpk(float lo, float hi) {
  unsigned r;
  asm("v_cvt_pk_bf16_f32 %0, %1, %2" : "=v"(r) : "v"(lo), "v"(hi));
  return r;
}
union U8 { unsigned u[4]; short8 s; };
__device__ __forceinline__ short8 mk8(unsigned a, unsigned b, unsigned c, unsigned d) {
  U8 t; t.u[0] = a; t.u[1] = b; t.u[2] = c; t.u[3] = d; return t.s;
}

// 4-lane (cross-quad) transpose of 4 packed-bf16 words:
// in:  lane(l16,q) holds pairs (4q,4q+1),(4q+2,4q+3),(16+4q,+1),(16+4q+2,+3)
// out: lane(l16,q) holds pairs (8q,8q+1),(8q+2,8q+3),(8q+4,8q+5),(8q+6,8q+7)
__device__ __forceinline__ void quad_transpose(unsigned& w0, unsigned& w1,
                                               unsigned& w2, unsigned& w3,
                                               int quad) {
  unsigned s0 = (quad & 2) ? w0 : w2;
  unsigned s1 = (quad & 2) ? w1 : w3;
  s0 = (unsigned)__shfl_xor((int)s0, 32);
  s1 = (unsigned)__shfl_xor((int)s1, 32);
  if (quad & 2) { w0 = s0; w1 = s1; } else { w2 = s0; w3 = s1; }
  unsigned t0 = (quad & 1) ? w0 : w2;
  unsigned t1 = (quad & 1) ? w1 : w3;
  t0 = (unsigned)__shfl_xor((int)t0, 16);
  t1 = (unsigned)__shfl_xor((int)t1, 16);
  if (quad & 1) { w0 = t0; w1 = t1; } else { w2 = t0; w3 = t1; }
}

// ---------------- prep: pack weights transposed [n][k] bf16, fold SCALE*L2E into Wq ----------------
__global__ void prep_weights(const float* __restrict__ qkv_w,
                             const float* __restrict__ qkv_b,
                             const float* __restrict__ proj_w,
                             short* __restrict__ wpack,   // [6][3][32][192] bf16
                             float* __restrict__ bpack,   // [6][3][32] f32
                             short* __restrict__ WpT)     // [192][192] bf16 (n,k)
{
  int i0 = blockIdx.x * blockDim.x + threadIdx.x;
  int stride = gridDim.x * blockDim.x;
  for (int idx = i0; idx < 110592; idx += stride) {
    int k = idx % 192;
    int t = idx / 192;
    int n = t % 32;
    int mat = (t / 32) % 3;
    int h = t / 96;
    float v = qkv_w[k * 576 + mat * 192 + h * 32 + n];
    if (mat == 0) v *= SCALE * L2E;      // exp2-domain logits
    wpack[idx] = f2bf(v);
  }
  for (int idx = i0; idx < 36864; idx += stride) {
    int k = idx % 192;
    int n = idx / 192;
    WpT[idx] = f2bf(proj_w[k * 192 + n]);
  }
  for (int idx = i0; idx < 576; idx += stride) {
    int d = idx % 32;
    int mat = (idx / 32) % 3;
    int h = idx / 96;
    float v = qkv_b[mat * 192 + h * 32 + d];
    if (mat == 0) v *= SCALE * L2E;
    bpack[idx] = v;
  }
}

// ---------------- prep: gathered rel-pos bias, padded to 352 keys, prescaled by L2E ----------------
__global__ void prep_bias(const float* __restrict__ bias_table,  // (2197,6)
                          const int* __restrict__ rpi,           // (343,343)
                          short* __restrict__ biasP)             // [6][343][352] bf16
{
  int p = blockIdx.x * blockDim.x + threadIdx.x;
  int h = blockIdx.y;
  if (p < N_TOK * NPAD) {
    int q = p / NPAD, k = p - q * NPAD;
    short v = 0;
    if (k < N_TOK) v = f2bf(bias_table[(size_t)rpi[q * N_TOK + k] * 6 + h] * L2E);
    biasP[(size_t)h * (N_TOK * NPAD) + p] = v;
  }
}

// ---------------- prep: mask padded to 352 keys, prescaled by L2E, pad = -1e30 (exp2 -> 0) ----------------
__global__ void prep_mask(const float* __restrict__ mask,   // (64,343,343)
                          float* __restrict__ maskP)        // (64,343,352)
{
  int i0 = blockIdx.x * blockDim.x + threadIdx.x;
  int stride = gridDim.x * blockDim.x;
  const int total = 64 * N_TOK * NPAD;
  for (int idx = i0; idx < total; idx += stride) {
    int k = idx % NPAD;
    int t = idx / NPAD;          // w*343 + q
    maskP[idx] = (k < N_TOK) ? mask[(size_t)t * N_TOK + k] * L2E : -1e30f;
  }
}

// ---------------- fused QKV + attention per (window b, head h) ----------------
// Operand-swapped MFMA: S^T = mfma(K,Q), O^T = mfma(V,P) -> q index lives on l16.
// LDS (shorts): Kl [352][40] @0 (14080) | Vt [32][360] @14080 (11520)
// total 25600 shorts = 51200 B -> 3 blocks/CU (12 waves/CU)
__global__ __launch_bounds__(256, 3) void fused_attn(
    const float* __restrict__ x,      // (512,343,192)
    const float* __restrict__ maskP,  // (64,343,352) prescaled, pad -1e30
    const short* __restrict__ wpack,  // [6][3][32][192] bf16
    const float* __restrict__ bpack,  // [6][3][32]
    const short* __restrict__ biasP,  // [6][343][352] bf16 prescaled
    short* __restrict__ AO)           // (512,343,192) bf16
{
  const int tid  = threadIdx.x;
  const int wave = tid >> 6;
  const int lane = tid & 63;
  const int l16  = lane & 15;
  const int quad = lane >> 4;

  // XCD swizzle: blocks sharing one mask window (8 b's x 6 h's) land on one XCD
  int id   = blockIdx.x;
  int xcd  = id & 7;
  int j    = id >> 3;               // 0..383
  int w_id = xcd * 8 + (j / 48);    // 0..63
  int r    = j % 48;
  int h    = r % 6;
  int b    = (r / 6) * 64 + w_id;

  extern __shared__ short smem_s[];
  short* Kl = smem_s;                // [352][40]  (row = key token, col = d)
  short* Vt = smem_s + 14080;        // [32][360]  (row = d, col = token)

  const float* bsrc = bpack + h * 96;
  float bqA[4], bqB[4], bkA[4], bkB[4];
#pragma unroll
  for (int rg = 0; rg < 4; ++rg) {
    bqA[rg] = bsrc[quad * 4 + rg];
    bqB[rg] = bsrc[16 + quad * 4 + rg];
    bkA[rg] = bsrc[32 + quad * 4 + rg];
    bkB[rg] = bsrc[48 + quad * 4 + rg];
  }
  const float bv0 = bsrc[64 + l16], bv1 = bsrc[80 + l16];

  // ---- Phase 1: Q,K,V = x @ W (per head). Q,K operand-swapped (token on l16). ----
  const float* xb = x + (size_t)b * (N_TOK * EMB);
  const short* wh = wpack + h * 18432;   // [mat][32][192]
  unsigned qreg[6][4];                   // Q rows: lane(l16,q) = Q[tok=r0+l16][d-pairs]

#pragma unroll
  for (int ch = 0; ch < 6; ++ch) {
    int r0 = ch * 64 + wave * 16;
    if (r0 >= NPAD) continue;            // ch=5 waves 2,3
    int row = r0 + l16;
    bool rok = row < N_TOK;
    const float* xr = xb + (size_t)row * EMB;

    short8 af[6];
#pragma unroll
    for (int kk = 0; kk < 6; ++kk) {
      const float* xp = xr + kk * 32 + quad * 8;
      floatx4 a0 = rok ? *(const floatx4*)xp       : (floatx4){0.f, 0.f, 0.f, 0.f};
      floatx4 a1 = rok ? *(const floatx4*)(xp + 4) : (floatx4){0.f, 0.f, 0.f, 0.f};
      af[kk] = mk8(cvtpk(a0[0], a0[1]), cvtpk(a0[2], a0[3]),
                   cvtpk(a1[0], a1[1]), cvtpk(a1[2], a1[3]));
    }

    // mat 0: Q, swapped -> lane holds Q[tok=row][d=quad*4+rg (+16)]
    {
      const short* wb = wh;
      floatx4 acc0 = {0.f,0.f,0.f,0.f}, acc1 = {0.f,0.f,0.f,0.f};
#pragma unroll
      for (int kk = 0; kk < 6; ++kk) {
        short8 b0 = *(const short8*)(wb + l16 * 192 + kk * 32 + quad * 8);
        short8 b1 = *(const short8*)(wb + (16 + l16) * 192 + kk * 32 + quad * 8);
        acc0 = __builtin_amdgcn_mfma_f32_16x16x32_bf16(b0, af[kk], acc0, 0, 0, 0);
        acc1 = __builtin_amdgcn_mfma_f32_16x16x32_bf16(b1, af[kk], acc1, 0, 0, 0);
      }
      qreg[ch][0] = cvtpk(acc0[0] + bqA[0], acc0[1] + bqA[1]);
      qreg[ch][1] = cvtpk(acc0[2] + bqA[2], acc0[3] + bqA[3]);
      qreg[ch][2] = cvtpk(acc1[0] + bqB[0], acc1[1] + bqB[1]);
      qreg[ch][3] = cvtpk(acc1[2] + bqB[2], acc1[3] + bqB[3]);
    }
    // mat 1: K, swapped -> vectorized row store Kl[tok][d]
    {
      const short* wb = wh + 6144;
      floatx4 acc0 = {0.f,0.f,0.f,0.f}, acc1 = {0.f,0.f,0.f,0.f};
#pragma unroll
      for (int kk = 0; kk < 6; ++kk) {
        short8 b0 = *(const short8*)(wb + l16 * 192 + kk * 32 + quad * 8);
        short8 b1 = *(const short8*)(wb + (16 + l16) * 192 + kk * 32 + quad * 8);
        acc0 = __builtin_amdgcn_mfma_f32_16x16x32_bf16(b0, af[kk], acc0, 0, 0, 0);
        acc1 = __builtin_amdgcn_mfma_f32_16x16x32_bf16(b1, af[kk], acc1, 0, 0, 0);
      }
      unsigned c0 = cvtpk(acc0[0] + bkA[0], acc0[1] + bkA[1]);
      unsigned c1 = cvtpk(acc0[2] + bkA[2], acc0[3] + bkA[3]);
      unsigned c2 = cvtpk(acc1[0] + bkB[0], acc1[1] + bkB[1]);
      unsigned c3 = cvtpk(acc1[2] + bkB[2], acc1[3] + bkB[3]);
      if (!rok) { c0 = 0u; c1 = 0u; c2 = 0u; c3 = 0u; }   // pad keys -> K = 0
      uint2v p0 = {c0, c1}, p1 = {c2, c3};
      *(uint2v*)(Kl + row * 40 + quad * 4)      = p0;
      *(uint2v*)(Kl + row * 40 + 16 + quad * 4) = p1;
    }
    // mat 2: V, unswapped -> Vt[d][tok] store vectorized over tokens
    {
      const short* wb = wh + 12288;
      floatx4 acc0 = {0.f,0.f,0.f,0.f}, acc1 = {0.f,0.f,0.f,0.f};
#pragma unroll
      for (int kk = 0; kk < 6; ++kk) {
        short8 b0 = *(const short8*)(wb + l16 * 192 + kk * 32 + quad * 8);
        short8 b1 = *(const short8*)(wb + (16 + l16) * 192 + kk * 32 + quad * 8);
        acc0 = __builtin_amdgcn_mfma_f32_16x16x32_bf16(af[kk], b0, acc0, 0, 0, 0);
        acc1 = __builtin_amdgcn_mfma_f32_16x16x32_bf16(af[kk], b1, acc1, 0, 0, 0);
      }
      int mg = r0 + quad * 4;
      float t0 = (mg + 0 < N_TOK) ? acc0[0] + bv0 : 0.f;
      float t1 = (mg + 1 < N_TOK) ? acc0[1] + bv0 : 0.f;
      float t2 = (mg + 2 < N_TOK) ? acc0[2] + bv0 : 0.f;
      float t3 = (mg + 3 < N_TOK) ? acc0[3] + bv0 : 0.f;
      float u0 = (mg + 0 < N_TOK) ? acc1[0] + bv1 : 0.f;
      float u1 = (mg + 1 < N_TOK) ? acc1[1] + bv1 : 0.f;
      float u2 = (mg + 2 < N_TOK) ? acc1[2] + bv1 : 0.f;
      float u3 = (mg + 3 < N_TOK) ? acc1[3] + bv1 : 0.f;
      uint2v sv0 = {cvtpk(t0, t1), cvtpk(t2, t3)};
      uint2v sv1 = {cvtpk(u0, u1), cvtpk(u2, u3)};
      *(uint2v*)(Vt + l16 * 360 + mg)        = sv0;
      *(uint2v*)(Vt + (16 + l16) * 360 + mg) = sv1;
    }
  }
  __syncthreads();

  // ---- Phase 2: per-wave 16-query chunks; q on l16; streamed softmax ----
  const float* mwin = maskP + (size_t)(b & 63) * (N_TOK * NPAD);
  const short* bhed = biasP + (size_t)h * (N_TOK * NPAD);

#pragma unroll
  for (int jx = 0; jx < 6; ++jx) {
    int c = jx * 4 + wave;
    if (c >= 22) continue;
    const int m0 = c * 16;

    // Q C-layout -> A/B-frag layout, in registers (4 shfl_xor)
    unsigned qw0 = qreg[jx][0], qw1 = qreg[jx][1], qw2 = qreg[jx][2], qw3 = qreg[jx][3];
    quad_transpose(qw0, qw1, qw2, qw3, quad);
    short8 qf = mk8(qw0, qw1, qw2, qw3);

    const int q  = m0 + l16;
    const int qc = (q < N_TOK) ? q : (N_TOK - 1);
    const float* mrow = mwin + (size_t)qc * NPAD;
    const short* brow = bhed + (size_t)qc * NPAD;

    float rsum = 0.f;
    floatx4 o0 = {0.f,0.f,0.f,0.f}, o1 = {0.f,0.f,0.f,0.f};

    // prefetch mask/bias for group 0 (vector loads: keys contiguous per lane)
    floatx4 nm0 = *(const floatx4*)(mrow + quad * 4);
    floatx4 nm1 = *(const floatx4*)(mrow + 16 + quad * 4);
    short4v nb0 = *(const short4v*)(brow + quad * 4);
    short4v nb1 = *(const short4v*)(brow + 16 + quad * 4);

#pragma unroll 2
    for (int g = 0; g < 11; ++g) {
      const int k0 = g * 32;
      floatx4 xm0 = nm0, xm1 = nm1;
      short4v xb0 = nb0, xb1 = nb1;
      if (g < 10) {
        nm0 = *(const floatx4*)(mrow + k0 + 32 + quad * 4);
        nm1 = *(const floatx4*)(mrow + k0 + 48 + quad * 4);
        nb0 = *(const short4v*)(brow + k0 + 32 + quad * 4);
        nb1 = *(const short4v*)(brow + k0 + 48 + quad * 4);
      }

      short8 kf0 = *(const short8*)(Kl + (k0 + l16) * 40 + quad * 8);
      short8 kf1 = *(const short8*)(Kl + (k0 + 16 + l16) * 40 + quad * 8);
      short8 vf0 = *(const short8*)(Vt + l16 * 360 + k0 + quad * 8);
      short8 vf1 = *(const short8*)(Vt + (16 + l16) * 360 + k0 + quad * 8);

      floatx4 zz = {0.f,0.f,0.f,0.f};
      floatx4 s0 = __builtin_amdgcn_mfma_f32_16x16x32_bf16(kf0, qf, zz, 0, 0, 0);
      floatx4 s1 = __builtin_amdgcn_mfma_f32_16x16x32_bf16(kf1, qf, zz, 0, 0, 0);

      float e0r[4], e1r[4];
#pragma unroll
      for (int rg = 0; rg < 4; ++rg) {
        e0r[rg] = __builtin_amdgcn_exp2f(s0[rg] + (xm0[rg] + bf2f(xb0[rg])));
        e1r[rg] = __builtin_amdgcn_exp2f(s1[rg] + (xm1[rg] + bf2f(xb1[rg])));
        rsum += e0r[rg] + e1r[rg];
      }
      unsigned w0 = cvtpk(e0r[0], e0r[1]);
      unsigned w1 = cvtpk(e0r[2], e0r[3]);
      unsigned w2 = cvtpk(e1r[0], e1r[1]);
      unsigned w3 = cvtpk(e1r[2], e1r[3]);
      quad_transpose(w0, w1, w2, w3, quad);
      short8 pf = mk8(w0, w1, w2, w3);

      o0 = __builtin_amdgcn_mfma_f32_16x16x32_bf16(vf0, pf, o0, 0, 0, 0);
      o1 = __builtin_amdgcn_mfma_f32_16x16x32_bf16(vf1, pf, o1, 0, 0, 0);
    }

    // full row sum: partials live on 4 quads of same l16
    rsum += __shfl_xor(rsum, 16);
    rsum += __shfl_xor(rsum, 32);
    float rinv = 1.0f / rsum;

    if (q < N_TOK) {
      short* dst = AO + ((size_t)b * N_TOK + q) * EMB + h * HD;
      uint2v d0 = {cvtpk(o0[0] * rinv, o0[1] * rinv), cvtpk(o0[2] * rinv, o0[3] * rinv)};
      uint2v d1 = {cvtpk(o1[0] * rinv, o1[1] * rinv), cvtpk(o1[2] * rinv, o1[3] * rinv)};
      *(uint2v*)(dst + quad * 4)      = d0;
      *(uint2v*)(dst + 16 + quad * 4) = d1;
    }
  }
}

// ---------------- final projection GEMM: (175616,192) @ (192,192) + b ----------------
__global__ __launch_bounds__(256) void proj_gemm(
    const short* __restrict__ AO,     // bf16 (M,192)
    const short* __restrict__ WpT,    // bf16 [n][k]
    const float* __restrict__ proj_b,
    float* __restrict__ out)
{
  __shared__ short As[64 * 200];
  const int tid  = threadIdx.x;
  const int wave = tid >> 6;
  const int lane = tid & 63;
  const int l16  = lane & 15;
  const int quad = lane >> 4;
  const int mb = blockIdx.x;

  const short* Ab = AO + (size_t)mb * (64 * EMB);
  for (int i = tid * 8; i < 64 * EMB; i += 2048) {
    uint4 va = *(const uint4*)(Ab + i);
    int rr = i / EMB, cc = i - rr * EMB;
    *(uint4*)(As + rr * 200 + cc) = va;
  }
  __syncthreads();

  short8 af[6];
#pragma unroll
  for (int kk = 0; kk < 6; ++kk)
    af[kk] = *(const short8*)(As + (wave * 16 + l16) * 200 + kk * 32 + quad * 8);

#pragma unroll 1
  for (int nt = 0; nt < 12; ++nt) {
    floatx4 acc = {0.f, 0.f, 0.f, 0.f};
#pragma unroll
    for (int kk = 0; kk < 6; ++kk) {
      short8 bf = *(const short8*)(WpT + (nt * 16 + l16) * EMB + kk * 32 + quad * 8);
      acc = __builtin_amdgcn_mfma_f32_16x16x32_bf16(af[kk], bf, acc, 0, 0, 0);
    }
    int colg = nt * 16 + l16;
    float pb = proj_b[colg];
    int mrow = mb * 64 + wave * 16 + quad * 4;
#pragma unroll
    for (int reg = 0; reg < 4; ++reg) {
      out[(size_t)(mrow + reg) * EMB + colg] = acc[reg] + pb;
    }
  }
}

extern "C" void kernel_launch(void* const* d_in, const int* in_sizes, int n_in,
                              void* d_out, int out_size, void* d_ws, size_t ws_size,
                              hipStream_t stream) {
  (void)in_sizes; (void)n_in; (void)out_size; (void)ws_size;
  const float* x        = (const float*)d_in[0];
  const float* mask     = (const float*)d_in[1];
  const float* qkv_w    = (const float*)d_in[2];
  const float* qkv_b    = (const float*)d_in[3];
  const float* proj_w   = (const float*)d_in[4];
  const float* proj_b   = (const float*)d_in[5];
  const float* bias_tab = (const float*)d_in[6];
  const int*   rpi      = (const int*)d_in[7];

  char* ws = (char*)d_ws;
  short* wpack = (short*)(ws);                  // 221184 B
  float* bpack = (float*)(ws + 221184);         // 2304 B
  short* WpT   = (short*)(ws + 223488);         // 73728 B
  short* biasP = (short*)(ws + 297216);         // 6*343*352*2 = 1448832 B
  float* maskP = (float*)(ws + 1746048);        // 64*343*352*4 = 30908416 B
  short* AO    = (short*)(ws + 32654464);       // 67436544 B -> total ~95.5 MB

  hipLaunchKernelGGL(prep_weights, dim3(128), dim3(256), 0, stream,
                     qkv_w, qkv_b, proj_w, wpack, bpack, WpT);
  hipLaunchKernelGGL(prep_bias, dim3(472, 6), dim3(256), 0, stream,
                     bias_tab, rpi, biasP);
  hipLaunchKernelGGL(prep_mask, dim3(2048), dim3(256), 0, stream,
                     mask, maskP);

  const int lds_bytes = 51200;
  (void)hipFuncSetAttribute((const void*)fused_attn,
                            hipFuncAttributeMaxDynamicSharedMemorySize, lds_bytes);
  hipLaunchKernelGGL(fused_attn, dim3(3072), dim3(256), lds_bytes, stream,
                     x, maskP, wpack, bpack, biasP, AO);

  hipLaunchKernelGGL(proj_gemm, dim3(2744), dim3(256), 0, stream,
                     AO, WpT, proj_b, (float*)d_out);
}

// Round 3
// 782.557 us; speedup vs baseline: 1.1760x; 1.1760x over previous
//
#include <hip/hip_runtime.h>
#include <stdint.h>

#define N_TOK 343
#define NPAD  352          // 22*16
#define EMB   192
#define HD    32
#define SCALE 0.17677669529663689f
#define L2E   1.44269504088896341f

typedef __attribute__((ext_vector_type(8))) short short8;   // 8 bf16 (4 VGPRs)
typedef __attribute__((ext_vector_type(4))) short short4v;  // 4 bf16 (2 VGPRs)
typedef __attribute__((ext_vector_type(2))) unsigned uint2v;
typedef __attribute__((ext_vector_type(4))) float floatx4;  // MFMA C/D

__device__ __forceinline__ short f2bf(float f) {
  union { float f; unsigned u; } v; v.f = f;
  unsigned r = v.u + 0x7fffu + ((v.u >> 16) & 1u);  // RNE, finite inputs
  return (short)(r >> 16);
}
__device__ __forceinline__ float bf2f(short s) {
  union { unsigned u; float f; } v;
  v.u = ((unsigned)(unsigned short)s) << 16;
  return v.f;
}
__device__ __forceinline__ unsigned cvtpk(float lo, float hi) {
  unsigned r;
  asm("v_cvt_pk_bf16_f32 %0, %1, %2" : "=v"(r) : "v"(lo), "v"(hi));
  return r;
}
union U8 { unsigned u[4]; short8 s; };
__device__ __forceinline__ short8 mk8(unsigned a, unsigned b, unsigned c, unsigned d) {
  U8 t; t.u[0] = a; t.u[1] = b; t.u[2] = c; t.u[3] = d; return t.s;
}

// 4-lane (cross-quad) transpose of 4 packed-bf16 words:
// in:  lane(l16,q) holds pairs (4q,4q+1),(4q+2,4q+3),(16+4q,+1),(16+4q+2,+3)
// out: lane(l16,q) holds pairs (8q,8q+1),(8q+2,8q+3),(8q+4,8q+5),(8q+6,8q+7)
__device__ __forceinline__ void quad_transpose(unsigned& w0, unsigned& w1,
                                               unsigned& w2, unsigned& w3,
                                               int quad) {
  unsigned s0 = (quad & 2) ? w0 : w2;
  unsigned s1 = (quad & 2) ? w1 : w3;
  s0 = (unsigned)__shfl_xor((int)s0, 32);
  s1 = (unsigned)__shfl_xor((int)s1, 32);
  if (quad & 2) { w0 = s0; w1 = s1; } else { w2 = s0; w3 = s1; }
  unsigned t0 = (quad & 1) ? w0 : w2;
  unsigned t1 = (quad & 1) ? w1 : w3;
  t0 = (unsigned)__shfl_xor((int)t0, 16);
  t1 = (unsigned)__shfl_xor((int)t1, 16);
  if (quad & 1) { w0 = t0; w1 = t1; } else { w2 = t0; w3 = t1; }
}

// ---------------- prep: pack weights transposed [n][k] bf16, fold SCALE*L2E into Wq ----------------
__global__ void prep_weights(const float* __restrict__ qkv_w,
                             const float* __restrict__ qkv_b,
                             const float* __restrict__ proj_w,
                             short* __restrict__ wpack,   // [6][3][32][192] bf16
                             float* __restrict__ bpack,   // [6][3][32] f32
                             short* __restrict__ WpT)     // [192][192] bf16 (n,k)
{
  int i0 = blockIdx.x * blockDim.x + threadIdx.x;
  int stride = gridDim.x * blockDim.x;
  for (int idx = i0; idx < 110592; idx += stride) {
    int k = idx % 192;
    int t = idx / 192;
    int n = t % 32;
    int mat = (t / 32) % 3;
    int h = t / 96;
    float v = qkv_w[k * 576 + mat * 192 + h * 32 + n];
    if (mat == 0) v *= SCALE * L2E;      // exp2-domain logits
    wpack[idx] = f2bf(v);
  }
  for (int idx = i0; idx < 36864; idx += stride) {
    int k = idx % 192;
    int n = idx / 192;
    WpT[idx] = f2bf(proj_w[k * 192 + n]);
  }
  for (int idx = i0; idx < 576; idx += stride) {
    int d = idx % 32;
    int mat = (idx / 32) % 3;
    int h = idx / 96;
    float v = qkv_b[mat * 192 + h * 32 + d];
    if (mat == 0) v *= SCALE * L2E;
    bpack[idx] = v;
  }
}

// ---------------- prep: gathered rel-pos bias, padded to 352 keys, prescaled by L2E ----------------
__global__ void prep_bias(const float* __restrict__ bias_table,  // (2197,6)
                          const int* __restrict__ rpi,           // (343,343)
                          short* __restrict__ biasP)             // [6][343][352] bf16
{
  int p = blockIdx.x * blockDim.x + threadIdx.x;
  int h = blockIdx.y;
  if (p < N_TOK * NPAD) {
    int q = p / NPAD, k = p - q * NPAD;
    short v = 0;
    if (k < N_TOK) v = f2bf(bias_table[(size_t)rpi[q * N_TOK + k] * 6 + h] * L2E);
    biasP[(size_t)h * (N_TOK * NPAD) + p] = v;
  }
}

// ---------------- prep: mask padded to 352 keys, prescaled by L2E, pad = -1e30 (exp2 -> 0) ----------------
__global__ void prep_mask(const float* __restrict__ mask,   // (64,343,343)
                          float* __restrict__ maskP)        // (64,343,352)
{
  int i0 = blockIdx.x * blockDim.x + threadIdx.x;
  int stride = gridDim.x * blockDim.x;
  const int total = 64 * N_TOK * NPAD;
  for (int idx = i0; idx < total; idx += stride) {
    int k = idx % NPAD;
    int t = idx / NPAD;          // w*343 + q
    maskP[idx] = (k < N_TOK) ? mask[(size_t)t * N_TOK + k] * L2E : -1e30f;
  }
}

// ---------------- fused QKV + attention per (window b, head h) ----------------
// Phase 1: head weights staged ONCE into LDS (padded stride 200 -> <=2-way bank
// aliasing, free); all B-fragments come from ds_read_b128 instead of 216 global
// loads/wave. K,V results held in registers until Ws is dead (Ws aliases Kl/Vt).
// Phase 2: identical to the verified round-1 kernel.
// LDS: Kl [352][40] @0 (28160 B) | Vt [32][360] @14080sh (23040 B) = 51200 B
//      Ws [3][32][200] @0 (38400 B) -- phase-1 only, aliases Kl/Vt
// -> 3 blocks/CU (12 waves/CU)
__global__ __launch_bounds__(256, 3) void fused_attn(
    const float* __restrict__ x,      // (512,343,192)
    const float* __restrict__ maskP,  // (64,343,352) prescaled, pad -1e30
    const short* __restrict__ wpack,  // [6][3][32][192] bf16
    const float* __restrict__ bpack,  // [6][3][32]
    const short* __restrict__ biasP,  // [6][343][352] bf16 prescaled
    short* __restrict__ AO)           // (512,343,192) bf16
{
  const int tid  = threadIdx.x;
  const int wave = tid >> 6;
  const int lane = tid & 63;
  const int l16  = lane & 15;
  const int quad = lane >> 4;

  // XCD swizzle: blocks sharing one mask window (8 b's x 6 h's) land on one XCD
  int id   = blockIdx.x;
  int xcd  = id & 7;
  int j    = id >> 3;               // 0..383
  int w_id = xcd * 8 + (j / 48);    // 0..63
  int r    = j % 48;
  int h    = r % 6;
  int b    = (r / 6) * 64 + w_id;

  extern __shared__ short smem_s[];
  short* Kl = smem_s;                // [352][40]  (row = key token, col = d)
  short* Vt = smem_s + 14080;        // [32][360]  (row = d, col = token)
  short* Ws = smem_s;                // [3][32][200] phase-1 weights (aliases Kl/Vt)

  // ---- stage this head's weights into LDS (one 36.9 KB copy per block) ----
  {
    const short* whsrc = wpack + h * 18432;   // [3][32][192] contiguous
#pragma unroll
    for (int i = 0; i < 9; ++i) {
      int p = (i * 256 + tid) * 8;            // 8 shorts, never crosses a row
      int row = p / 192;                       // mat*32 + n
      int col = p - row * 192;
      short8 w = *(const short8*)(whsrc + p);
      *(short8*)(Ws + row * 200 + col) = w;
    }
  }

  const float* bsrc = bpack + h * 96;
  float bqA[4], bqB[4], bkA[4], bkB[4];
#pragma unroll
  for (int rg = 0; rg < 4; ++rg) {
    bqA[rg] = bsrc[quad * 4 + rg];
    bqB[rg] = bsrc[16 + quad * 4 + rg];
    bkA[rg] = bsrc[32 + quad * 4 + rg];
    bkB[rg] = bsrc[48 + quad * 4 + rg];
  }
  const float bv0 = bsrc[64 + l16], bv1 = bsrc[80 + l16];

  __syncthreads();   // Ws staged

  // ---- Phase 1: Q,K,V = x @ W (per head). Q,K operand-swapped (token on l16). ----
  const float* xb = x + (size_t)b * (N_TOK * EMB);
  unsigned qreg[6][4];   // Q: lane(l16,q) holds Q[d-pairs][tok=l16]
  unsigned kreg[6][4];   // K rows, packed; written to LDS after Ws dies
  unsigned vreg[6][4];   // V cols, packed

#pragma unroll
  for (int ch = 0; ch < 6; ++ch) {
    int r0 = ch * 64 + wave * 16;
    if (r0 >= NPAD) continue;            // ch=5 waves 2,3
    int row = r0 + l16;
    bool rok = row < N_TOK;
    const float* xr = xb + (size_t)row * EMB;

    short8 af[6];
#pragma unroll
    for (int kk = 0; kk < 6; ++kk) {
      const float* xp = xr + kk * 32 + quad * 8;
      floatx4 a0 = rok ? *(const floatx4*)xp       : (floatx4){0.f, 0.f, 0.f, 0.f};
      floatx4 a1 = rok ? *(const floatx4*)(xp + 4) : (floatx4){0.f, 0.f, 0.f, 0.f};
      af[kk] = mk8(cvtpk(a0[0], a0[1]), cvtpk(a0[2], a0[3]),
                   cvtpk(a1[0], a1[1]), cvtpk(a1[2], a1[3]));
    }

    // mat 0: Q, swapped
    {
      floatx4 acc0 = {0.f,0.f,0.f,0.f}, acc1 = {0.f,0.f,0.f,0.f};
#pragma unroll
      for (int kk = 0; kk < 6; ++kk) {
        short8 b0 = *(const short8*)(Ws + l16 * 200 + kk * 32 + quad * 8);
        short8 b1 = *(const short8*)(Ws + (16 + l16) * 200 + kk * 32 + quad * 8);
        acc0 = __builtin_amdgcn_mfma_f32_16x16x32_bf16(b0, af[kk], acc0, 0, 0, 0);
        acc1 = __builtin_amdgcn_mfma_f32_16x16x32_bf16(b1, af[kk], acc1, 0, 0, 0);
      }
      qreg[ch][0] = cvtpk(acc0[0] + bqA[0], acc0[1] + bqA[1]);
      qreg[ch][1] = cvtpk(acc0[2] + bqA[2], acc0[3] + bqA[3]);
      qreg[ch][2] = cvtpk(acc1[0] + bqB[0], acc1[1] + bqB[1]);
      qreg[ch][3] = cvtpk(acc1[2] + bqB[2], acc1[3] + bqB[3]);
    }
    // mat 1: K, swapped -> packed rows kept in registers
    {
      const short* wb = Ws + 32 * 200;
      floatx4 acc0 = {0.f,0.f,0.f,0.f}, acc1 = {0.f,0.f,0.f,0.f};
#pragma unroll
      for (int kk = 0; kk < 6; ++kk) {
        short8 b0 = *(const short8*)(wb + l16 * 200 + kk * 32 + quad * 8);
        short8 b1 = *(const short8*)(wb + (16 + l16) * 200 + kk * 32 + quad * 8);
        acc0 = __builtin_amdgcn_mfma_f32_16x16x32_bf16(b0, af[kk], acc0, 0, 0, 0);
        acc1 = __builtin_amdgcn_mfma_f32_16x16x32_bf16(b1, af[kk], acc1, 0, 0, 0);
      }
      unsigned c0 = cvtpk(acc0[0] + bkA[0], acc0[1] + bkA[1]);
      unsigned c1 = cvtpk(acc0[2] + bkA[2], acc0[3] + bkA[3]);
      unsigned c2 = cvtpk(acc1[0] + bkB[0], acc1[1] + bkB[1]);
      unsigned c3 = cvtpk(acc1[2] + bkB[2], acc1[3] + bkB[3]);
      if (!rok) { c0 = 0u; c1 = 0u; c2 = 0u; c3 = 0u; }   // pad keys -> K = 0
      kreg[ch][0] = c0; kreg[ch][1] = c1; kreg[ch][2] = c2; kreg[ch][3] = c3;
    }
    // mat 2: V, unswapped -> packed cols kept in registers
    {
      const short* wb = Ws + 64 * 200;
      floatx4 acc0 = {0.f,0.f,0.f,0.f}, acc1 = {0.f,0.f,0.f,0.f};
#pragma unroll
      for (int kk = 0; kk < 6; ++kk) {
        short8 b0 = *(const short8*)(wb + l16 * 200 + kk * 32 + quad * 8);
        short8 b1 = *(const short8*)(wb + (16 + l16) * 200 + kk * 32 + quad * 8);
        acc0 = __builtin_amdgcn_mfma_f32_16x16x32_bf16(af[kk], b0, acc0, 0, 0, 0);
        acc1 = __builtin_amdgcn_mfma_f32_16x16x32_bf16(af[kk], b1, acc1, 0, 0, 0);
      }
      int mg = r0 + quad * 4;
      float t0 = (mg + 0 < N_TOK) ? acc0[0] + bv0 : 0.f;
      float t1 = (mg + 1 < N_TOK) ? acc0[1] + bv0 : 0.f;
      float t2 = (mg + 2 < N_TOK) ? acc0[2] + bv0 : 0.f;
      float t3 = (mg + 3 < N_TOK) ? acc0[3] + bv0 : 0.f;
      float u0 = (mg + 0 < N_TOK) ? acc1[0] + bv1 : 0.f;
      float u1 = (mg + 1 < N_TOK) ? acc1[1] + bv1 : 0.f;
      float u2 = (mg + 2 < N_TOK) ? acc1[2] + bv1 : 0.f;
      float u3 = (mg + 3 < N_TOK) ? acc1[3] + bv1 : 0.f;
      vreg[ch][0] = cvtpk(t0, t1); vreg[ch][1] = cvtpk(t2, t3);
      vreg[ch][2] = cvtpk(u0, u1); vreg[ch][3] = cvtpk(u2, u3);
    }
  }

  __syncthreads();   // all Ws reads complete -> safe to overwrite with Kl/Vt

  // ---- spill K,V registers to their LDS layouts ----
#pragma unroll
  for (int ch = 0; ch < 6; ++ch) {
    int r0 = ch * 64 + wave * 16;
    if (r0 >= NPAD) continue;
    int row = r0 + l16;
    uint2v p0 = {kreg[ch][0], kreg[ch][1]};
    uint2v p1 = {kreg[ch][2], kreg[ch][3]};
    *(uint2v*)(Kl + row * 40 + quad * 4)      = p0;
    *(uint2v*)(Kl + row * 40 + 16 + quad * 4) = p1;
    int mg = r0 + quad * 4;
    uint2v sv0 = {vreg[ch][0], vreg[ch][1]};
    uint2v sv1 = {vreg[ch][2], vreg[ch][3]};
    *(uint2v*)(Vt + l16 * 360 + mg)        = sv0;
    *(uint2v*)(Vt + (16 + l16) * 360 + mg) = sv1;
  }
  __syncthreads();

  // ---- Phase 2: per-wave 16-query chunks; q on l16; streamed softmax ----
  const float* mwin = maskP + (size_t)(b & 63) * (N_TOK * NPAD);
  const short* bhed = biasP + (size_t)h * (N_TOK * NPAD);

#pragma unroll
  for (int jx = 0; jx < 6; ++jx) {
    int c = jx * 4 + wave;
    if (c >= 22) continue;
    const int m0 = c * 16;

    // Q C-layout -> A/B-frag layout, in registers (4 shfl_xor)
    unsigned qw0 = qreg[jx][0], qw1 = qreg[jx][1], qw2 = qreg[jx][2], qw3 = qreg[jx][3];
    quad_transpose(qw0, qw1, qw2, qw3, quad);
    short8 qf = mk8(qw0, qw1, qw2, qw3);

    const int q  = m0 + l16;
    const int qc = (q < N_TOK) ? q : (N_TOK - 1);
    const float* mrow = mwin + (size_t)qc * NPAD;
    const short* brow = bhed + (size_t)qc * NPAD;

    float rsum = 0.f;
    floatx4 o0 = {0.f,0.f,0.f,0.f}, o1 = {0.f,0.f,0.f,0.f};

    // prefetch mask/bias for group 0 (vector loads: keys contiguous per lane)
    floatx4 nm0 = *(const floatx4*)(mrow + quad * 4);
    floatx4 nm1 = *(const floatx4*)(mrow + 16 + quad * 4);
    short4v nb0 = *(const short4v*)(brow + quad * 4);
    short4v nb1 = *(const short4v*)(brow + 16 + quad * 4);

#pragma unroll 2
    for (int g = 0; g < 11; ++g) {
      const int k0 = g * 32;
      floatx4 xm0 = nm0, xm1 = nm1;
      short4v xb0 = nb0, xb1 = nb1;
      if (g < 10) {
        nm0 = *(const floatx4*)(mrow + k0 + 32 + quad * 4);
        nm1 = *(const floatx4*)(mrow + k0 + 48 + quad * 4);
        nb0 = *(const short4v*)(brow + k0 + 32 + quad * 4);
        nb1 = *(const short4v*)(brow + k0 + 48 + quad * 4);
      }

      short8 kf0 = *(const short8*)(Kl + (k0 + l16) * 40 + quad * 8);
      short8 kf1 = *(const short8*)(Kl + (k0 + 16 + l16) * 40 + quad * 8);
      short8 vf0 = *(const short8*)(Vt + l16 * 360 + k0 + quad * 8);
      short8 vf1 = *(const short8*)(Vt + (16 + l16) * 360 + k0 + quad * 8);

      floatx4 zz = {0.f,0.f,0.f,0.f};
      floatx4 s0 = __builtin_amdgcn_mfma_f32_16x16x32_bf16(kf0, qf, zz, 0, 0, 0);
      floatx4 s1 = __builtin_amdgcn_mfma_f32_16x16x32_bf16(kf1, qf, zz, 0, 0, 0);

      float e0r[4], e1r[4];
#pragma unroll
      for (int rg = 0; rg < 4; ++rg) {
        e0r[rg] = __builtin_amdgcn_exp2f(s0[rg] + (xm0[rg] + bf2f(xb0[rg])));
        e1r[rg] = __builtin_amdgcn_exp2f(s1[rg] + (xm1[rg] + bf2f(xb1[rg])));
        rsum += e0r[rg] + e1r[rg];
      }
      unsigned w0 = cvtpk(e0r[0], e0r[1]);
      unsigned w1 = cvtpk(e0r[2], e0r[3]);
      unsigned w2 = cvtpk(e1r[0], e1r[1]);
      unsigned w3 = cvtpk(e1r[2], e1r[3]);
      quad_transpose(w0, w1, w2, w3, quad);
      short8 pf = mk8(w0, w1, w2, w3);

      o0 = __builtin_amdgcn_mfma_f32_16x16x32_bf16(vf0, pf, o0, 0, 0, 0);
      o1 = __builtin_amdgcn_mfma_f32_16x16x32_bf16(vf1, pf, o1, 0, 0, 0);
    }

    // full row sum: partials live on 4 quads of same l16
    rsum += __shfl_xor(rsum, 16);
    rsum += __shfl_xor(rsum, 32);
    float rinv = 1.0f / rsum;

    if (q < N_TOK) {
      short* dst = AO + ((size_t)b * N_TOK + q) * EMB + h * HD;
      uint2v d0 = {cvtpk(o0[0] * rinv, o0[1] * rinv), cvtpk(o0[2] * rinv, o0[3] * rinv)};
      uint2v d1 = {cvtpk(o1[0] * rinv, o1[1] * rinv), cvtpk(o1[2] * rinv, o1[3] * rinv)};
      *(uint2v*)(dst + quad * 4)      = d0;
      *(uint2v*)(dst + 16 + quad * 4) = d1;
    }
  }
}

// ---------------- final projection GEMM: (175616,192) @ (192,192) + b ----------------
__global__ __launch_bounds__(256) void proj_gemm(
    const short* __restrict__ AO,     // bf16 (M,192)
    const short* __restrict__ WpT,    // bf16 [n][k]
    const float* __restrict__ proj_b,
    float* __restrict__ out)
{
  __shared__ short As[64 * 200];
  const int tid  = threadIdx.x;
  const int wave = tid >> 6;
  const int lane = tid & 63;
  const int l16  = lane & 15;
  const int quad = lane >> 4;
  const int mb = blockIdx.x;

  const short* Ab = AO + (size_t)mb * (64 * EMB);
  for (int i = tid * 8; i < 64 * EMB; i += 2048) {
    uint4 va = *(const uint4*)(Ab + i);
    int rr = i / EMB, cc = i - rr * EMB;
    *(uint4*)(As + rr * 200 + cc) = va;
  }
  __syncthreads();

  short8 af[6];
#pragma unroll
  for (int kk = 0; kk < 6; ++kk)
    af[kk] = *(const short8*)(As + (wave * 16 + l16) * 200 + kk * 32 + quad * 8);

#pragma unroll 1
  for (int nt = 0; nt < 12; ++nt) {
    floatx4 acc = {0.f, 0.f, 0.f, 0.f};
#pragma unroll
    for (int kk = 0; kk < 6; ++kk) {
      short8 bf = *(const short8*)(WpT + (nt * 16 + l16) * EMB + kk * 32 + quad * 8);
      acc = __builtin_amdgcn_mfma_f32_16x16x32_bf16(af[kk], bf, acc, 0, 0, 0);
    }
    int colg = nt * 16 + l16;
    float pb = proj_b[colg];
    int mrow = mb * 64 + wave * 16 + quad * 4;
#pragma unroll
    for (int reg = 0; reg < 4; ++reg) {
      out[(size_t)(mrow + reg) * EMB + colg] = acc[reg] + pb;
    }
  }
}

extern "C" void kernel_launch(void* const* d_in, const int* in_sizes, int n_in,
                              void* d_out, int out_size, void* d_ws, size_t ws_size,
                              hipStream_t stream) {
  (void)in_sizes; (void)n_in; (void)out_size; (void)ws_size;
  const float* x        = (const float*)d_in[0];
  const float* mask     = (const float*)d_in[1];
  const float* qkv_w    = (const float*)d_in[2];
  const float* qkv_b    = (const float*)d_in[3];
  const float* proj_w   = (const float*)d_in[4];
  const float* proj_b   = (const float*)d_in[5];
  const float* bias_tab = (const float*)d_in[6];
  const int*   rpi      = (const int*)d_in[7];

  char* ws = (char*)d_ws;
  short* wpack = (short*)(ws);                  // 221184 B
  float* bpack = (float*)(ws + 221184);         // 2304 B
  short* WpT   = (short*)(ws + 223488);         // 73728 B
  short* biasP = (short*)(ws + 297216);         // 6*343*352*2 = 1448832 B
  float* maskP = (float*)(ws + 1746048);        // 64*343*352*4 = 30908416 B
  short* AO    = (short*)(ws + 32654464);       // 67436544 B -> total ~95.5 MB

  hipLaunchKernelGGL(prep_weights, dim3(128), dim3(256), 0, stream,
                     qkv_w, qkv_b, proj_w, wpack, bpack, WpT);
  hipLaunchKernelGGL(prep_bias, dim3(472, 6), dim3(256), 0, stream,
                     bias_tab, rpi, biasP);
  hipLaunchKernelGGL(prep_mask, dim3(2048), dim3(256), 0, stream,
                     mask, maskP);

  const int lds_bytes = 51200;
  (void)hipFuncSetAttribute((const void*)fused_attn,
                            hipFuncAttributeMaxDynamicSharedMemorySize, lds_bytes);
  hipLaunchKernelGGL(fused_attn, dim3(3072), dim3(256), lds_bytes, stream,
                     x, maskP, wpack, bpack, biasP, AO);

  hipLaunchKernelGGL(proj_gemm, dim3(2744), dim3(256), 0, stream,
                     AO, WpT, proj_b, (float*)d_out);
}

// Round 4
// 765.526 us; speedup vs baseline: 1.2021x; 1.0222x over previous
//
#include <hip/hip_runtime.h>
#include <stdint.h>

#define N_TOK 343
#define NPAD  352          // 22*16
#define EMB   192
#define HD    32
#define SCALE 0.17677669529663689f
#define L2E   1.44269504088896341f

typedef __attribute__((ext_vector_type(8))) short short8;   // 8 bf16 (4 VGPRs)
typedef __attribute__((ext_vector_type(4))) short short4v;  // 4 bf16 (2 VGPRs)
typedef __attribute__((ext_vector_type(2))) unsigned uint2v;
typedef __attribute__((ext_vector_type(4))) float floatx4;  // MFMA C/D

__device__ __forceinline__ short f2bf(float f) {
  union { float f; unsigned u; } v; v.f = f;
  unsigned r = v.u + 0x7fffu + ((v.u >> 16) & 1u);  // RNE, finite inputs
  return (short)(r >> 16);
}
__device__ __forceinline__ float bf2f(short s) {
  union { unsigned u; float f; } v;
  v.u = ((unsigned)(unsigned short)s) << 16;
  return v.f;
}
__device__ __forceinline__ unsigned cvtpk(float lo, float hi) {
  unsigned r;
  asm("v_cvt_pk_bf16_f32 %0, %1, %2" : "=v"(r) : "v"(lo), "v"(hi));
  return r;
}
union U8 { unsigned u[4]; short8 s; };
__device__ __forceinline__ short8 mk8(unsigned a, unsigned b, unsigned c, unsigned d) {
  U8 t; t.u[0] = a; t.u[1] = b; t.u[2] = c; t.u[3] = d; return t.s;
}

// 4-lane (cross-quad) transpose of 4 packed-bf16 words
__device__ __forceinline__ void quad_transpose(unsigned& w0, unsigned& w1,
                                               unsigned& w2, unsigned& w3,
                                               int quad) {
  unsigned s0 = (quad & 2) ? w0 : w2;
  unsigned s1 = (quad & 2) ? w1 : w3;
  s0 = (unsigned)__shfl_xor((int)s0, 32);
  s1 = (unsigned)__shfl_xor((int)s1, 32);
  if (quad & 2) { w0 = s0; w1 = s1; } else { w2 = s0; w3 = s1; }
  unsigned t0 = (quad & 1) ? w0 : w2;
  unsigned t1 = (quad & 1) ? w1 : w3;
  t0 = (unsigned)__shfl_xor((int)t0, 16);
  t1 = (unsigned)__shfl_xor((int)t1, 16);
  if (quad & 1) { w0 = t0; w1 = t1; } else { w2 = t0; w3 = t1; }
}

// ---------------- prep: pack weights transposed [n][k] bf16, fold SCALE*L2E into Wq ----------------
__global__ void prep_weights(const float* __restrict__ qkv_w,
                             const float* __restrict__ qkv_b,
                             const float* __restrict__ proj_w,
                             short* __restrict__ wpack,   // [6][3][32][192] bf16
                             float* __restrict__ bpack,   // [6][3][32] f32
                             short* __restrict__ WpT)     // [192][192] bf16 (n,k)
{
  int i0 = blockIdx.x * blockDim.x + threadIdx.x;
  int stride = gridDim.x * blockDim.x;
  for (int idx = i0; idx < 110592; idx += stride) {
    int k = idx % 192;
    int t = idx / 192;
    int n = t % 32;
    int mat = (t / 32) % 3;
    int h = t / 96;
    float v = qkv_w[k * 576 + mat * 192 + h * 32 + n];
    if (mat == 0) v *= SCALE * L2E;      // exp2-domain logits
    wpack[idx] = f2bf(v);
  }
  for (int idx = i0; idx < 36864; idx += stride) {
    int k = idx % 192;
    int n = idx / 192;
    WpT[idx] = f2bf(proj_w[k * 192 + n]);
  }
  for (int idx = i0; idx < 576; idx += stride) {
    int d = idx % 32;
    int mat = (idx / 32) % 3;
    int h = idx / 96;
    float v = qkv_b[mat * 192 + h * 32 + d];
    if (mat == 0) v *= SCALE * L2E;
    bpack[idx] = v;
  }
}

// ---------------- prep: gathered rel-pos bias, padded to 352 keys, prescaled by L2E ----------------
__global__ void prep_bias(const float* __restrict__ bias_table,  // (2197,6)
                          const int* __restrict__ rpi,           // (343,343)
                          short* __restrict__ biasP)             // [6][343][352] bf16
{
  int p = blockIdx.x * blockDim.x + threadIdx.x;
  int h = blockIdx.y;
  if (p < N_TOK * NPAD) {
    int q = p / NPAD, k = p - q * NPAD;
    short v = 0;
    if (k < N_TOK) v = f2bf(bias_table[(size_t)rpi[q * N_TOK + k] * 6 + h] * L2E);
    biasP[(size_t)h * (N_TOK * NPAD) + p] = v;
  }
}

// ---------------- prep: mask padded to 352 keys, prescaled by L2E, pad = -1e30 (exp2 -> 0) ----------------
__global__ void prep_mask(const float* __restrict__ mask,   // (64,343,343)
                          float* __restrict__ maskP)        // (64,343,352)
{
  int i0 = blockIdx.x * blockDim.x + threadIdx.x;
  int stride = gridDim.x * blockDim.x;
  const int total = 64 * N_TOK * NPAD;
  for (int idx = i0; idx < total; idx += stride) {
    int k = idx % NPAD;
    int t = idx / NPAD;          // w*343 + q
    maskP[idx] = (k < N_TOK) ? mask[(size_t)t * N_TOK + k] * L2E : -1e30f;
  }
}

// ---------------- fused QKV + attention per (window b, head h) ----------------
// Phase 1: Wk,Wv staged ONCE into LDS (24.6 KB, aliases Vt region); Wq read from
// global (12.3 KB -> L1-resident after chunk 0). K written directly to Kl (no
// kreg); only V held in registers until Ws dies -> no scratch spill.
// Phase 2: identical to the verified round-1 kernel.
// LDS (shorts): Kl [352][40] @0 | Vt [32][360] @14080 | Ws [2][32][200] @14080
// dynamic total 53760 B -> 3 blocks/CU (12 waves/CU)
__global__ __launch_bounds__(256, 3) void fused_attn(
    const float* __restrict__ x,      // (512,343,192)
    const float* __restrict__ maskP,  // (64,343,352) prescaled, pad -1e30
    const short* __restrict__ wpack,  // [6][3][32][192] bf16
    const float* __restrict__ bpack,  // [6][3][32]
    const short* __restrict__ biasP,  // [6][343][352] bf16 prescaled
    short* __restrict__ AO)           // (512,343,192) bf16
{
  const int tid  = threadIdx.x;
  const int wave = tid >> 6;
  const int lane = tid & 63;
  const int l16  = lane & 15;
  const int quad = lane >> 4;

  // XCD swizzle: blocks sharing one mask window (8 b's x 6 h's) land on one XCD
  int id   = blockIdx.x;
  int xcd  = id & 7;
  int j    = id >> 3;               // 0..383
  int w_id = xcd * 8 + (j / 48);    // 0..63
  int r    = j % 48;
  int h    = r % 6;
  int b    = (r / 6) * 64 + w_id;

  extern __shared__ short smem_s[];
  short* Kl = smem_s;                // [352][40]  (row = key token, col = d)
  short* Vt = smem_s + 14080;        // [32][360]  (row = d, col = token)
  short* Ws = smem_s + 14080;        // [2][32][200] Wk,Wv (phase-1 only, aliases Vt)

  // ---- stage Wk,Wv into LDS (24.6 KB per block) ----
  {
    const short* wsrc = wpack + h * 18432 + 6144;   // mats 1,2: [2][32][192]
#pragma unroll
    for (int i = 0; i < 6; ++i) {
      int p = (i * 256 + tid) * 8;            // 8 shorts, never crosses a row
      int row = p / 192;                       // mat*32 + n  (mat: 0=K,1=V)
      int col = p - row * 192;
      short8 w = *(const short8*)(wsrc + p);
      *(short8*)(Ws + row * 200 + col) = w;
    }
  }

  const float* bsrc = bpack + h * 96;
  float bqA[4], bqB[4], bkA[4], bkB[4];
#pragma unroll
  for (int rg = 0; rg < 4; ++rg) {
    bqA[rg] = bsrc[quad * 4 + rg];
    bqB[rg] = bsrc[16 + quad * 4 + rg];
    bkA[rg] = bsrc[32 + quad * 4 + rg];
    bkB[rg] = bsrc[48 + quad * 4 + rg];
  }
  const float bv0 = bsrc[64 + l16], bv1 = bsrc[80 + l16];

  __syncthreads();   // Ws staged

  // ---- Phase 1: Q,K,V = x @ W (per head). Q,K operand-swapped (token on l16). ----
  const float* xb = x + (size_t)b * (N_TOK * EMB);
  const short* wq = wpack + h * 18432;   // Wq from global (L1-resident)
  unsigned qreg[6][4];   // Q: lane(l16,q) holds Q[d-pairs][tok=l16]
  unsigned vreg[6][4];   // V cols, packed; written to LDS after Ws dies

#pragma unroll
  for (int ch = 0; ch < 6; ++ch) {
    int r0 = ch * 64 + wave * 16;
    if (r0 >= NPAD) continue;            // ch=5 waves 2,3
    int row = r0 + l16;
    bool rok = row < N_TOK;
    const float* xr = xb + (size_t)row * EMB;

    short8 af[6];
#pragma unroll
    for (int kk = 0; kk < 6; ++kk) {
      const float* xp = xr + kk * 32 + quad * 8;
      floatx4 a0 = rok ? *(const floatx4*)xp       : (floatx4){0.f, 0.f, 0.f, 0.f};
      floatx4 a1 = rok ? *(const floatx4*)(xp + 4) : (floatx4){0.f, 0.f, 0.f, 0.f};
      af[kk] = mk8(cvtpk(a0[0], a0[1]), cvtpk(a0[2], a0[3]),
                   cvtpk(a1[0], a1[1]), cvtpk(a1[2], a1[3]));
    }

    // mat 0: Q, swapped; weights from GLOBAL (12.3 KB, L1-hot after chunk 0)
    {
      floatx4 acc0 = {0.f,0.f,0.f,0.f}, acc1 = {0.f,0.f,0.f,0.f};
#pragma unroll
      for (int kk = 0; kk < 6; ++kk) {
        short8 b0 = *(const short8*)(wq + l16 * 192 + kk * 32 + quad * 8);
        short8 b1 = *(const short8*)(wq + (16 + l16) * 192 + kk * 32 + quad * 8);
        acc0 = __builtin_amdgcn_mfma_f32_16x16x32_bf16(b0, af[kk], acc0, 0, 0, 0);
        acc1 = __builtin_amdgcn_mfma_f32_16x16x32_bf16(b1, af[kk], acc1, 0, 0, 0);
      }
      qreg[ch][0] = cvtpk(acc0[0] + bqA[0], acc0[1] + bqA[1]);
      qreg[ch][1] = cvtpk(acc0[2] + bqA[2], acc0[3] + bqA[3]);
      qreg[ch][2] = cvtpk(acc1[0] + bqB[0], acc1[1] + bqB[1]);
      qreg[ch][3] = cvtpk(acc1[2] + bqB[2], acc1[3] + bqB[3]);
    }
    // mat 1: K, swapped; weights from LDS; rows written DIRECTLY to Kl
    {
      floatx4 acc0 = {0.f,0.f,0.f,0.f}, acc1 = {0.f,0.f,0.f,0.f};
#pragma unroll
      for (int kk = 0; kk < 6; ++kk) {
        short8 b0 = *(const short8*)(Ws + l16 * 200 + kk * 32 + quad * 8);
        short8 b1 = *(const short8*)(Ws + (16 + l16) * 200 + kk * 32 + quad * 8);
        acc0 = __builtin_amdgcn_mfma_f32_16x16x32_bf16(b0, af[kk], acc0, 0, 0, 0);
        acc1 = __builtin_amdgcn_mfma_f32_16x16x32_bf16(b1, af[kk], acc1, 0, 0, 0);
      }
      unsigned c0 = cvtpk(acc0[0] + bkA[0], acc0[1] + bkA[1]);
      unsigned c1 = cvtpk(acc0[2] + bkA[2], acc0[3] + bkA[3]);
      unsigned c2 = cvtpk(acc1[0] + bkB[0], acc1[1] + bkB[1]);
      unsigned c3 = cvtpk(acc1[2] + bkB[2], acc1[3] + bkB[3]);
      if (!rok) { c0 = 0u; c1 = 0u; c2 = 0u; c3 = 0u; }   // pad keys -> K = 0
      uint2v p0 = {c0, c1}, p1 = {c2, c3};
      *(uint2v*)(Kl + row * 40 + quad * 4)      = p0;
      *(uint2v*)(Kl + row * 40 + 16 + quad * 4) = p1;
    }
    // mat 2: V, unswapped; weights from LDS; packed cols kept in registers
    {
      const short* wb = Ws + 32 * 200;
      floatx4 acc0 = {0.f,0.f,0.f,0.f}, acc1 = {0.f,0.f,0.f,0.f};
#pragma unroll
      for (int kk = 0; kk < 6; ++kk) {
        short8 b0 = *(const short8*)(wb + l16 * 200 + kk * 32 + quad * 8);
        short8 b1 = *(const short8*)(wb + (16 + l16) * 200 + kk * 32 + quad * 8);
        acc0 = __builtin_amdgcn_mfma_f32_16x16x32_bf16(af[kk], b0, acc0, 0, 0, 0);
        acc1 = __builtin_amdgcn_mfma_f32_16x16x32_bf16(af[kk], b1, acc1, 0, 0, 0);
      }
      int mg = r0 + quad * 4;
      float t0 = (mg + 0 < N_TOK) ? acc0[0] + bv0 : 0.f;
      float t1 = (mg + 1 < N_TOK) ? acc0[1] + bv0 : 0.f;
      float t2 = (mg + 2 < N_TOK) ? acc0[2] + bv0 : 0.f;
      float t3 = (mg + 3 < N_TOK) ? acc0[3] + bv0 : 0.f;
      float u0 = (mg + 0 < N_TOK) ? acc1[0] + bv1 : 0.f;
      float u1 = (mg + 1 < N_TOK) ? acc1[1] + bv1 : 0.f;
      float u2 = (mg + 2 < N_TOK) ? acc1[2] + bv1 : 0.f;
      float u3 = (mg + 3 < N_TOK) ? acc1[3] + bv1 : 0.f;
      vreg[ch][0] = cvtpk(t0, t1); vreg[ch][1] = cvtpk(t2, t3);
      vreg[ch][2] = cvtpk(u0, u1); vreg[ch][3] = cvtpk(u2, u3);
    }
  }

  __syncthreads();   // all Ws reads complete -> safe to overwrite with Vt

  // ---- spill V registers to Vt layout ----
#pragma unroll
  for (int ch = 0; ch < 6; ++ch) {
    int r0 = ch * 64 + wave * 16;
    if (r0 >= NPAD) continue;
    int mg = r0 + quad * 4;
    uint2v sv0 = {vreg[ch][0], vreg[ch][1]};
    uint2v sv1 = {vreg[ch][2], vreg[ch][3]};
    *(uint2v*)(Vt + l16 * 360 + mg)        = sv0;
    *(uint2v*)(Vt + (16 + l16) * 360 + mg) = sv1;
  }
  __syncthreads();

  // ---- Phase 2: per-wave 16-query chunks; q on l16; streamed softmax ----
  const float* mwin = maskP + (size_t)(b & 63) * (N_TOK * NPAD);
  const short* bhed = biasP + (size_t)h * (N_TOK * NPAD);

#pragma unroll
  for (int jx = 0; jx < 6; ++jx) {
    int c = jx * 4 + wave;
    if (c >= 22) continue;
    const int m0 = c * 16;

    // Q C-layout -> A/B-frag layout, in registers (4 shfl_xor)
    unsigned qw0 = qreg[jx][0], qw1 = qreg[jx][1], qw2 = qreg[jx][2], qw3 = qreg[jx][3];
    quad_transpose(qw0, qw1, qw2, qw3, quad);
    short8 qf = mk8(qw0, qw1, qw2, qw3);

    const int q  = m0 + l16;
    const int qc = (q < N_TOK) ? q : (N_TOK - 1);
    const float* mrow = mwin + (size_t)qc * NPAD;
    const short* brow = bhed + (size_t)qc * NPAD;

    float rsum = 0.f;
    floatx4 o0 = {0.f,0.f,0.f,0.f}, o1 = {0.f,0.f,0.f,0.f};

    // prefetch mask/bias for group 0 (vector loads: keys contiguous per lane)
    floatx4 nm0 = *(const floatx4*)(mrow + quad * 4);
    floatx4 nm1 = *(const floatx4*)(mrow + 16 + quad * 4);
    short4v nb0 = *(const short4v*)(brow + quad * 4);
    short4v nb1 = *(const short4v*)(brow + 16 + quad * 4);

#pragma unroll 2
    for (int g = 0; g < 11; ++g) {
      const int k0 = g * 32;
      floatx4 xm0 = nm0, xm1 = nm1;
      short4v xb0 = nb0, xb1 = nb1;
      if (g < 10) {
        nm0 = *(const floatx4*)(mrow + k0 + 32 + quad * 4);
        nm1 = *(const floatx4*)(mrow + k0 + 48 + quad * 4);
        nb0 = *(const short4v*)(brow + k0 + 32 + quad * 4);
        nb1 = *(const short4v*)(brow + k0 + 48 + quad * 4);
      }

      short8 kf0 = *(const short8*)(Kl + (k0 + l16) * 40 + quad * 8);
      short8 kf1 = *(const short8*)(Kl + (k0 + 16 + l16) * 40 + quad * 8);
      short8 vf0 = *(const short8*)(Vt + l16 * 360 + k0 + quad * 8);
      short8 vf1 = *(const short8*)(Vt + (16 + l16) * 360 + k0 + quad * 8);

      floatx4 zz = {0.f,0.f,0.f,0.f};
      floatx4 s0 = __builtin_amdgcn_mfma_f32_16x16x32_bf16(kf0, qf, zz, 0, 0, 0);
      floatx4 s1 = __builtin_amdgcn_mfma_f32_16x16x32_bf16(kf1, qf, zz, 0, 0, 0);

      float e0r[4], e1r[4];
#pragma unroll
      for (int rg = 0; rg < 4; ++rg) {
        e0r[rg] = __builtin_amdgcn_exp2f(s0[rg] + (xm0[rg] + bf2f(xb0[rg])));
        e1r[rg] = __builtin_amdgcn_exp2f(s1[rg] + (xm1[rg] + bf2f(xb1[rg])));
        rsum += e0r[rg] + e1r[rg];
      }
      unsigned w0 = cvtpk(e0r[0], e0r[1]);
      unsigned w1 = cvtpk(e0r[2], e0r[3]);
      unsigned w2 = cvtpk(e1r[0], e1r[1]);
      unsigned w3 = cvtpk(e1r[2], e1r[3]);
      quad_transpose(w0, w1, w2, w3, quad);
      short8 pf = mk8(w0, w1, w2, w3);

      o0 = __builtin_amdgcn_mfma_f32_16x16x32_bf16(vf0, pf, o0, 0, 0, 0);
      o1 = __builtin_amdgcn_mfma_f32_16x16x32_bf16(vf1, pf, o1, 0, 0, 0);
    }

    // full row sum: partials live on 4 quads of same l16
    rsum += __shfl_xor(rsum, 16);
    rsum += __shfl_xor(rsum, 32);
    float rinv = 1.0f / rsum;

    if (q < N_TOK) {
      short* dst = AO + ((size_t)b * N_TOK + q) * EMB + h * HD;
      uint2v d0 = {cvtpk(o0[0] * rinv, o0[1] * rinv), cvtpk(o0[2] * rinv, o0[3] * rinv)};
      uint2v d1 = {cvtpk(o1[0] * rinv, o1[1] * rinv), cvtpk(o1[2] * rinv, o1[3] * rinv)};
      *(uint2v*)(dst + quad * 4)      = d0;
      *(uint2v*)(dst + 16 + quad * 4) = d1;
    }
  }
}

// ---------------- final projection GEMM: (175616,192) @ (192,192) + b ----------------
__global__ __launch_bounds__(256) void proj_gemm(
    const short* __restrict__ AO,     // bf16 (M,192)
    const short* __restrict__ WpT,    // bf16 [n][k]
    const float* __restrict__ proj_b,
    float* __restrict__ out)
{
  __shared__ short As[64 * 200];
  const int tid  = threadIdx.x;
  const int wave = tid >> 6;
  const int lane = tid & 63;
  const int l16  = lane & 15;
  const int quad = lane >> 4;
  const int mb = blockIdx.x;

  const short* Ab = AO + (size_t)mb * (64 * EMB);
  for (int i = tid * 8; i < 64 * EMB; i += 2048) {
    uint4 va = *(const uint4*)(Ab + i);
    int rr = i / EMB, cc = i - rr * EMB;
    *(uint4*)(As + rr * 200 + cc) = va;
  }
  __syncthreads();

  short8 af[6];
#pragma unroll
  for (int kk = 0; kk < 6; ++kk)
    af[kk] = *(const short8*)(As + (wave * 16 + l16) * 200 + kk * 32 + quad * 8);

#pragma unroll 1
  for (int nt = 0; nt < 12; ++nt) {
    floatx4 acc = {0.f, 0.f, 0.f, 0.f};
#pragma unroll
    for (int kk = 0; kk < 6; ++kk) {
      short8 bf = *(const short8*)(WpT + (nt * 16 + l16) * EMB + kk * 32 + quad * 8);
      acc = __builtin_amdgcn_mfma_f32_16x16x32_bf16(af[kk], bf, acc, 0, 0, 0);
    }
    int colg = nt * 16 + l16;
    float pb = proj_b[colg];
    int mrow = mb * 64 + wave * 16 + quad * 4;
#pragma unroll
    for (int reg = 0; reg < 4; ++reg) {
      out[(size_t)(mrow + reg) * EMB + colg] = acc[reg] + pb;
    }
  }
}

extern "C" void kernel_launch(void* const* d_in, const int* in_sizes, int n_in,
                              void* d_out, int out_size, void* d_ws, size_t ws_size,
                              hipStream_t stream) {
  (void)in_sizes; (void)n_in; (void)out_size; (void)ws_size;
  const float* x        = (const float*)d_in[0];
  const float* mask     = (const float*)d_in[1];
  const float* qkv_w    = (const float*)d_in[2];
  const float* qkv_b    = (const float*)d_in[3];
  const float* proj_w   = (const float*)d_in[4];
  const float* proj_b   = (const float*)d_in[5];
  const float* bias_tab = (const float*)d_in[6];
  const int*   rpi      = (const int*)d_in[7];

  char* ws = (char*)d_ws;
  short* wpack = (short*)(ws);                  // 221184 B
  float* bpack = (float*)(ws + 221184);         // 2304 B
  short* WpT   = (short*)(ws + 223488);         // 73728 B
  short* biasP = (short*)(ws + 297216);         // 6*343*352*2 = 1448832 B
  float* maskP = (float*)(ws + 1746048);        // 64*343*352*4 = 30908416 B
  short* AO    = (short*)(ws + 32654464);       // 67436544 B -> total ~95.5 MB

  hipLaunchKernelGGL(prep_weights, dim3(128), dim3(256), 0, stream,
                     qkv_w, qkv_b, proj_w, wpack, bpack, WpT);
  hipLaunchKernelGGL(prep_bias, dim3(472, 6), dim3(256), 0, stream,
                     bias_tab, rpi, biasP);
  hipLaunchKernelGGL(prep_mask, dim3(2048), dim3(256), 0, stream,
                     mask, maskP);

  const int lds_bytes = 53760;   // Kl 28160 + Ws(2x32x200)*2B = 25600
  (void)hipFuncSetAttribute((const void*)fused_attn,
                            hipFuncAttributeMaxDynamicSharedMemorySize, lds_bytes);
  hipLaunchKernelGGL(fused_attn, dim3(3072), dim3(256), lds_bytes, stream,
                     x, maskP, wpack, bpack, biasP, AO);

  hipLaunchKernelGGL(proj_gemm, dim3(2744), dim3(256), 0, stream,
                     AO, WpT, proj_b, (float*)d_out);
}